// Round 1
// baseline (1240.328 us; speedup 1.0000x reference)
//
#include <hip/hip_runtime.h>
#include <hip/hip_bf16.h>

#define N_ROWS 8192
#define DDIM 1024
#define HDIM 4096
#define ODIM 1024
#define NEXP 8

// ws layout (bytes)
#define O_XB      0ull
#define O_W1T     16777216ull
#define O_W2T     83886080ull
#define O_H       150994944ull
#define O_ROWSPE  293601280ull
#define O_WPE     293863424ull
#define O_SROWS   294125568ull
#define O_SW      294195200ull
#define O_CNT     294264832ull
#define O_AOFF    294264864ull
#define O_TOFF    294264904ull
#define WS_NEEDED 294264944ull

typedef short bf16x8 __attribute__((ext_vector_type(8)));
typedef float f32x4 __attribute__((ext_vector_type(4)));

__device__ __forceinline__ unsigned short f2bf(float f) {
  unsigned u = __float_as_uint(f);
  u = (u + 0x7fffu + ((u >> 16) & 1u)) >> 16;
  return (unsigned short)u;
}

__device__ __forceinline__ void async_cp16(const void* g, void* l) {
  __builtin_amdgcn_global_load_lds(
      (const __attribute__((address_space(1))) unsigned int*)g,
      (__attribute__((address_space(3))) unsigned int*)l, 16, 0, 0);
}

// ---- x fp32 -> bf16 ----
__global__ __launch_bounds__(256) void cvt_x_kernel(const float* __restrict__ x,
                                                    unsigned short* __restrict__ xb) {
  size_t i = ((size_t)blockIdx.x * 256 + threadIdx.x) * 8;
  float4 a = *(const float4*)(x + i);
  float4 b = *(const float4*)(x + i + 4);
  union { unsigned short s[8]; uint4 v; } u;
  u.s[0] = f2bf(a.x); u.s[1] = f2bf(a.y); u.s[2] = f2bf(a.z); u.s[3] = f2bf(a.w);
  u.s[4] = f2bf(b.x); u.s[5] = f2bf(b.y); u.s[6] = f2bf(b.z); u.s[7] = f2bf(b.w);
  *(uint4*)(xb + i) = u.v;
}

// ---- per-expert [R,C] fp32 -> [C,R] bf16 ----
__global__ __launch_bounds__(256) void transpose_cvt_kernel(const float* __restrict__ in,
                                                            unsigned short* __restrict__ out,
                                                            int R, int C) {
  __shared__ float t[64][65];
  size_t ebase = (size_t)blockIdx.z * R * C;
  int r0 = blockIdx.x * 64, c0 = blockIdx.y * 64;
  int tid = threadIdx.x;
  for (int i = tid; i < 4096; i += 256) {
    int r = i >> 6, c = i & 63;
    t[r][c] = in[ebase + (size_t)(r0 + r) * C + (c0 + c)];
  }
  __syncthreads();
  for (int i = tid; i < 4096; i += 256) {
    int c = i >> 6, r = i & 63;
    out[ebase + (size_t)(c0 + c) * R + (r0 + r)] = f2bf(t[r][c]);
  }
}

// ---- gating: fp32 GEMV + softmax/T + top2 + renorm; append to per-expert lists ----
__global__ __launch_bounds__(256) void gate_kernel(const float* __restrict__ x,
                                                   const float* __restrict__ Wg,
                                                   const float* __restrict__ bg,
                                                   int* __restrict__ cnt,
                                                   int* __restrict__ rowsPE,
                                                   float* __restrict__ wPE) {
  __shared__ float wgt[NEXP * DDIM];  // transposed [e][d]
  int tid = threadIdx.x;
  for (int i = tid; i < NEXP * DDIM; i += 256) {
    int d = i >> 3, e = i & 7;
    wgt[e * DDIM + d] = Wg[i];
  }
  __syncthreads();
  int lane = tid & 63;
  int row = blockIdx.x * 4 + (tid >> 6);
  const float* xr = x + (size_t)row * DDIM;
  float acc[NEXP];
#pragma unroll
  for (int e = 0; e < NEXP; e++) acc[e] = 0.f;
  for (int j = 0; j < DDIM / 64; j++) {
    int d = j * 64 + lane;
    float xv = xr[d];
#pragma unroll
    for (int e = 0; e < NEXP; e++) acc[e] += xv * wgt[e * DDIM + d];
  }
#pragma unroll
  for (int e = 0; e < NEXP; e++) {
#pragma unroll
    for (int off = 32; off > 0; off >>= 1) acc[e] += __shfl_xor(acc[e], off, 64);
  }
  if (lane == 0) {
    float s[NEXP], p[NEXP];
    float m = -1e30f;
#pragma unroll
    for (int e = 0; e < NEXP; e++) {
      s[e] = (acc[e] + bg[e]) * 0.36787944117144233f;  // 1/TEMP, TEMP=e
      m = s[e] > m ? s[e] : m;
    }
    float sum = 0.f;
#pragma unroll
    for (int e = 0; e < NEXP; e++) { p[e] = __expf(s[e] - m); sum += p[e]; }
    float inv = 1.0f / sum;
#pragma unroll
    for (int e = 0; e < NEXP; e++) p[e] *= inv;
    int i1 = 0;
#pragma unroll
    for (int e = 1; e < NEXP; e++) if (p[e] > p[i1]) i1 = e;
    int i2 = (i1 == 0) ? 1 : 0;
#pragma unroll
    for (int e = 0; e < NEXP; e++) if (e != i1 && p[e] > p[i2]) i2 = e;
    float denom = p[i1] + p[i2] + 1e-8f;
    float w1 = p[i1] / denom, w2 = p[i2] / denom;
    int pos1 = atomicAdd(&cnt[i1], 1);
    rowsPE[i1 * N_ROWS + pos1] = row; wPE[i1 * N_ROWS + pos1] = w1;
    int pos2 = atomicAdd(&cnt[i2], 1);
    rowsPE[i2 * N_ROWS + pos2] = row; wPE[i2 * N_ROWS + pos2] = w2;
  }
}

// ---- 128-aligned prefix offsets ----
__global__ void finalize_kernel(const int* __restrict__ cnt, int* __restrict__ aoff,
                                int* __restrict__ toff) {
  if (threadIdx.x == 0) {
    int a = 0, t = 0;
    for (int e = 0; e < NEXP; e++) {
      aoff[e] = a; toff[e] = t;
      int tiles = (cnt[e] + 127) >> 7;
      a += tiles << 7; t += tiles;
    }
    aoff[NEXP] = a; toff[NEXP] = t;
  }
}

// ---- compact per-expert lists into padded slot arrays ----
__global__ __launch_bounds__(256) void scatter_kernel(const int* __restrict__ cnt,
                                                      const int* __restrict__ aoff,
                                                      const int* __restrict__ rowsPE,
                                                      const float* __restrict__ wPE,
                                                      int* __restrict__ srows,
                                                      float* __restrict__ sw) {
  int e = blockIdx.x;
  int c = cnt[e];
  int padded = ((c + 127) >> 7) << 7;
  int a0 = aoff[e];
  for (int i = threadIdx.x; i < padded; i += 256) {
    if (i < c) { srows[a0 + i] = rowsPE[e * N_ROWS + i]; sw[a0 + i] = wPE[e * N_ROWS + i]; }
    else       { srows[a0 + i] = 0;                      sw[a0 + i] = 0.f; }
  }
}

// ---- grouped GEMM: 128x128 tile, 4 waves, 16x16x32 bf16 MFMA, async LDS staging ----
// A is [rows, KDIM] bf16 (gathered via srows for GEMM1), Bt is [E][NDIM][KDIM] bf16.
// RELU=true: Hout[slot][NDIM] = bf16(relu(acc + bias)); else atomicAdd(Out[row], w*(acc+bias)).
template <bool GATHER, bool RELU>
__global__ __launch_bounds__(256) void gemm_kernel(
    const unsigned short* __restrict__ A, const unsigned short* __restrict__ Bt,
    const float* __restrict__ bias, unsigned short* __restrict__ Hout,
    float* __restrict__ Out, const int* __restrict__ srows, const float* __restrict__ sw,
    const int* __restrict__ aoff, const int* __restrict__ toff, int KDIM, int NDIM) {
  __shared__ unsigned short lds[8192];  // A tile 128x32 @0, B tile 128x32 @4096 (ushorts)
  int bx = blockIdx.x;
  if (bx >= toff[NEXP]) return;
  int e = 0;
  while (toff[e + 1] <= bx) e++;
  int slot0 = aoff[e] + ((bx - toff[e]) << 7);
  int n0 = blockIdx.y << 7;
  const unsigned short* Bte = Bt + (size_t)e * NDIM * KDIM;

  int tid = threadIdx.x, wave = tid >> 6, lane = tid & 63;
  // staging: lane -> (row-in-issue, chunk-slot); XOR swizzle folded into global addr
  int ri = lane >> 2, cs = lane & 3;
  int kchunk = cs ^ ((ri & 3) ^ (ri >> 2));
  const unsigned short* aptr[2];
  const unsigned short* bptr[2];
#pragma unroll
  for (int j = 0; j < 2; j++) {
    int rt = wave * 32 + j * 16 + ri;
    int grow = GATHER ? srows[slot0 + rt] : (slot0 + rt);
    aptr[j] = A + (size_t)grow * KDIM + kchunk * 8;
    bptr[j] = Bte + (size_t)(n0 + rt) * KDIM + kchunk * 8;
  }
  unsigned short* ldsA = &lds[wave * 1024];
  unsigned short* ldsB = &lds[4096 + wave * 1024];

  // fragment read offsets (swizzle-aware)
  int l4 = lane & 15, quad = lane >> 4;
  int rchunk = quad ^ ((l4 & 3) ^ (l4 >> 2));
  int wm = wave >> 1, wn = wave & 1;
  int aoffs[4], boffs[4];
#pragma unroll
  for (int i = 0; i < 4; i++) {
    aoffs[i] = (wm * 64 + i * 16 + l4) * 32 + rchunk * 8;
    boffs[i] = 4096 + (wn * 64 + i * 16 + l4) * 32 + rchunk * 8;
  }

  f32x4 zero = {0.f, 0.f, 0.f, 0.f};
  f32x4 acc[4][4];
#pragma unroll
  for (int mi = 0; mi < 4; mi++)
#pragma unroll
    for (int ni = 0; ni < 4; ni++) acc[mi][ni] = zero;

  for (int k0 = 0; k0 < KDIM; k0 += 32) {
#pragma unroll
    for (int j = 0; j < 2; j++) {
      async_cp16(aptr[j] + k0, ldsA + j * 512);
      async_cp16(bptr[j] + k0, ldsB + j * 512);
    }
    __syncthreads();
    bf16x8 af[4], bfr[4];
#pragma unroll
    for (int i = 0; i < 4; i++) af[i] = *(const bf16x8*)&lds[aoffs[i]];
#pragma unroll
    for (int i = 0; i < 4; i++) bfr[i] = *(const bf16x8*)&lds[boffs[i]];
#pragma unroll
    for (int mi = 0; mi < 4; mi++)
#pragma unroll
      for (int ni = 0; ni < 4; ni++)
        acc[mi][ni] = __builtin_amdgcn_mfma_f32_16x16x32_bf16(af[mi], bfr[ni], acc[mi][ni], 0, 0, 0);
    __syncthreads();
  }

#pragma unroll
  for (int ni = 0; ni < 4; ni++) {
    int col = n0 + wn * 64 + ni * 16 + l4;
    float bv = bias[e * NDIM + col];
#pragma unroll
    for (int mi = 0; mi < 4; mi++) {
#pragma unroll
      for (int r = 0; r < 4; r++) {
        int srow = slot0 + wm * 64 + mi * 16 + quad * 4 + r;
        float v = acc[mi][ni][r] + bv;
        if (RELU) {
          v = v > 0.f ? v : 0.f;
          Hout[(size_t)srow * NDIM + col] = f2bf(v);
        } else {
          atomicAdd(&Out[(size_t)srows[srow] * ODIM + col], sw[srow] * v);
        }
      }
    }
  }
}

extern "C" void kernel_launch(void* const* d_in, const int* in_sizes, int n_in,
                              void* d_out, int out_size, void* d_ws, size_t ws_size,
                              hipStream_t stream) {
  const float* x  = (const float*)d_in[0];
  const float* Wg = (const float*)d_in[1];
  const float* bg = (const float*)d_in[2];
  const float* W1 = (const float*)d_in[3];
  const float* b1 = (const float*)d_in[4];
  const float* W2 = (const float*)d_in[5];
  const float* b2 = (const float*)d_in[6];
  float* out = (float*)d_out;

  char* ws = (char*)d_ws;
  unsigned short* xb   = (unsigned short*)(ws + O_XB);
  unsigned short* W1t  = (unsigned short*)(ws + O_W1T);
  unsigned short* W2t  = (unsigned short*)(ws + O_W2T);
  unsigned short* hbuf = (unsigned short*)(ws + O_H);
  int*   rowsPE = (int*)(ws + O_ROWSPE);
  float* wPE    = (float*)(ws + O_WPE);
  int*   srows  = (int*)(ws + O_SROWS);
  float* swt    = (float*)(ws + O_SW);
  int*   cnt    = (int*)(ws + O_CNT);
  int*   aoff   = (int*)(ws + O_AOFF);
  int*   toff   = (int*)(ws + O_TOFF);

  hipMemsetAsync(d_out, 0, (size_t)N_ROWS * ODIM * sizeof(float), stream);
  if (ws_size < WS_NEEDED) return;  // loud fail: output stays zero
  hipMemsetAsync(cnt, 0, NEXP * sizeof(int), stream);

  cvt_x_kernel<<<dim3((N_ROWS * DDIM) / (256 * 8)), 256, 0, stream>>>(x, xb);
  transpose_cvt_kernel<<<dim3(DDIM / 64, HDIM / 64, NEXP), 256, 0, stream>>>(W1, W1t, DDIM, HDIM);
  transpose_cvt_kernel<<<dim3(HDIM / 64, ODIM / 64, NEXP), 256, 0, stream>>>(W2, W2t, HDIM, ODIM);
  gate_kernel<<<dim3(N_ROWS / 4), 256, 0, stream>>>(x, Wg, bg, cnt, rowsPE, wPE);
  finalize_kernel<<<1, 64, 0, stream>>>(cnt, aoff, toff);
  scatter_kernel<<<dim3(NEXP), 256, 0, stream>>>(cnt, aoff, rowsPE, wPE, srows, swt);
  gemm_kernel<true, true><<<dim3(136, HDIM / 128), 256, 0, stream>>>(
      xb, W1t, b1, hbuf, nullptr, srows, swt, aoff, toff, DDIM, HDIM);
  gemm_kernel<false, false><<<dim3(136, ODIM / 128), 256, 0, stream>>>(
      hbuf, W2t, b2, nullptr, out, srows, swt, aoff, toff, HDIM, ODIM);
}

// Round 2
// 1093.601 us; speedup vs baseline: 1.1342x; 1.1342x over previous
//
#include <hip/hip_runtime.h>
#include <hip/hip_bf16.h>

#define N_ROWS 8192
#define DDIM 1024
#define HDIM 4096
#define ODIM 1024
#define NEXP 8

// ws layout (bytes)
#define O_XB      0ull
#define O_W1T     16777216ull
#define O_W2T     83886080ull
#define O_H       150994944ull
#define O_ROWSPE  293601280ull
#define O_WPE     293863424ull
#define O_SROWS   294125568ull
#define O_SW      294195200ull
#define O_CNT     294264832ull
#define O_AOFF    294264864ull
#define O_TOFF    294264904ull
#define WS_NEEDED 294264944ull

typedef short bf16x8 __attribute__((ext_vector_type(8)));
typedef float f32x4 __attribute__((ext_vector_type(4)));

__device__ __forceinline__ unsigned short f2bf(float f) {
  unsigned u = __float_as_uint(f);
  u = (u + 0x7fffu + ((u >> 16) & 1u)) >> 16;
  return (unsigned short)u;
}

__device__ __forceinline__ void async_cp16(const void* g, void* l) {
  __builtin_amdgcn_global_load_lds(
      (const __attribute__((address_space(1))) unsigned int*)g,
      (__attribute__((address_space(3))) unsigned int*)l, 16, 0, 0);
}

// ---- x fp32 -> bf16 ----
__global__ __launch_bounds__(256) void cvt_x_kernel(const float* __restrict__ x,
                                                    unsigned short* __restrict__ xb) {
  size_t i = ((size_t)blockIdx.x * 256 + threadIdx.x) * 8;
  float4 a = *(const float4*)(x + i);
  float4 b = *(const float4*)(x + i + 4);
  union { unsigned short s[8]; uint4 v; } u;
  u.s[0] = f2bf(a.x); u.s[1] = f2bf(a.y); u.s[2] = f2bf(a.z); u.s[3] = f2bf(a.w);
  u.s[4] = f2bf(b.x); u.s[5] = f2bf(b.y); u.s[6] = f2bf(b.z); u.s[7] = f2bf(b.w);
  *(uint4*)(xb + i) = u.v;
}

// ---- per-expert [R,C] fp32 -> [C,R] bf16 ----
__global__ __launch_bounds__(256) void transpose_cvt_kernel(const float* __restrict__ in,
                                                            unsigned short* __restrict__ out,
                                                            int R, int C) {
  __shared__ float t[64][65];
  size_t ebase = (size_t)blockIdx.z * R * C;
  int r0 = blockIdx.x * 64, c0 = blockIdx.y * 64;
  int tid = threadIdx.x;
  for (int i = tid; i < 4096; i += 256) {
    int r = i >> 6, c = i & 63;
    t[r][c] = in[ebase + (size_t)(r0 + r) * C + (c0 + c)];
  }
  __syncthreads();
  for (int i = tid; i < 4096; i += 256) {
    int c = i >> 6, r = i & 63;
    out[ebase + (size_t)(c0 + c) * R + (r0 + r)] = f2bf(t[r][c]);
  }
}

// ---- gating: fp32 GEMV + softmax/T + top2 + renorm; append to per-expert lists ----
__global__ __launch_bounds__(256) void gate_kernel(const float* __restrict__ x,
                                                   const float* __restrict__ Wg,
                                                   const float* __restrict__ bg,
                                                   int* __restrict__ cnt,
                                                   int* __restrict__ rowsPE,
                                                   float* __restrict__ wPE) {
  __shared__ float wgt[NEXP * DDIM];  // transposed [e][d]
  int tid = threadIdx.x;
  for (int i = tid; i < NEXP * DDIM; i += 256) {
    int d = i >> 3, e = i & 7;
    wgt[e * DDIM + d] = Wg[i];
  }
  __syncthreads();
  int lane = tid & 63;
  int row = blockIdx.x * 4 + (tid >> 6);
  const float* xr = x + (size_t)row * DDIM;
  float acc[NEXP];
#pragma unroll
  for (int e = 0; e < NEXP; e++) acc[e] = 0.f;
  for (int j = 0; j < DDIM / 64; j++) {
    int d = j * 64 + lane;
    float xv = xr[d];
#pragma unroll
    for (int e = 0; e < NEXP; e++) acc[e] += xv * wgt[e * DDIM + d];
  }
#pragma unroll
  for (int e = 0; e < NEXP; e++) {
#pragma unroll
    for (int off = 32; off > 0; off >>= 1) acc[e] += __shfl_xor(acc[e], off, 64);
  }
  if (lane == 0) {
    float s[NEXP], p[NEXP];
    float m = -1e30f;
#pragma unroll
    for (int e = 0; e < NEXP; e++) {
      s[e] = (acc[e] + bg[e]) * 0.36787944117144233f;  // 1/TEMP, TEMP=e
      m = s[e] > m ? s[e] : m;
    }
    float sum = 0.f;
#pragma unroll
    for (int e = 0; e < NEXP; e++) { p[e] = __expf(s[e] - m); sum += p[e]; }
    float inv = 1.0f / sum;
#pragma unroll
    for (int e = 0; e < NEXP; e++) p[e] *= inv;
    int i1 = 0;
#pragma unroll
    for (int e = 1; e < NEXP; e++) if (p[e] > p[i1]) i1 = e;
    int i2 = (i1 == 0) ? 1 : 0;
#pragma unroll
    for (int e = 0; e < NEXP; e++) if (e != i1 && p[e] > p[i2]) i2 = e;
    float denom = p[i1] + p[i2] + 1e-8f;
    float w1 = p[i1] / denom, w2 = p[i2] / denom;
    int pos1 = atomicAdd(&cnt[i1], 1);
    rowsPE[i1 * N_ROWS + pos1] = row; wPE[i1 * N_ROWS + pos1] = w1;
    int pos2 = atomicAdd(&cnt[i2], 1);
    rowsPE[i2 * N_ROWS + pos2] = row; wPE[i2 * N_ROWS + pos2] = w2;
  }
}

// ---- 128-aligned prefix offsets ----
__global__ void finalize_kernel(const int* __restrict__ cnt, int* __restrict__ aoff,
                                int* __restrict__ toff) {
  if (threadIdx.x == 0) {
    int a = 0, t = 0;
    for (int e = 0; e < NEXP; e++) {
      aoff[e] = a; toff[e] = t;
      int tiles = (cnt[e] + 127) >> 7;
      a += tiles << 7; t += tiles;
    }
    aoff[NEXP] = a; toff[NEXP] = t;
  }
}

// ---- compact per-expert lists into padded slot arrays ----
__global__ __launch_bounds__(256) void scatter_kernel(const int* __restrict__ cnt,
                                                      const int* __restrict__ aoff,
                                                      const int* __restrict__ rowsPE,
                                                      const float* __restrict__ wPE,
                                                      int* __restrict__ srows,
                                                      float* __restrict__ sw) {
  int e = blockIdx.x;
  int c = cnt[e];
  int padded = ((c + 127) >> 7) << 7;
  int a0 = aoff[e];
  for (int i = threadIdx.x; i < padded; i += 256) {
    if (i < c) { srows[a0 + i] = rowsPE[e * N_ROWS + i]; sw[a0 + i] = wPE[e * N_ROWS + i]; }
    else       { srows[a0 + i] = 0;                      sw[a0 + i] = 0.f; }
  }
}

// ---- grouped GEMM: 128x128 tile, 4 waves, 16x16x32 bf16 MFMA ----
// Double-buffered async LDS staging; 1D grid with y (N-tile) fastest so that
// consecutive blocks share the A row-tile (L2/L3 reuse; A fetched from HBM once).
template <bool GATHER, bool RELU>
__global__ __launch_bounds__(256) void gemm_kernel(
    const unsigned short* __restrict__ A, const unsigned short* __restrict__ Bt,
    const float* __restrict__ bias, unsigned short* __restrict__ Hout,
    float* __restrict__ Out, const int* __restrict__ srows, const float* __restrict__ sw,
    const int* __restrict__ aoff, const int* __restrict__ toff, int KDIM, int NDIM, int nty) {
  __shared__ unsigned short lds[16384];  // 2 bufs x (A 128x32 @0 | B 128x32 @4096)
  int b = blockIdx.x;
  int xt = b / nty, yt = b - xt * nty;
  if (xt >= toff[NEXP]) return;
  int e = 0;
  while (toff[e + 1] <= xt) e++;
  int slot0 = aoff[e] + ((xt - toff[e]) << 7);
  int n0 = yt << 7;
  const unsigned short* Bte = Bt + (size_t)e * NDIM * KDIM;

  int tid = threadIdx.x, wave = tid >> 6, lane = tid & 63;
  // staging: lane -> (row-in-issue, chunk-slot); XOR swizzle folded into global addr
  int ri = lane >> 2, cs = lane & 3;
  int kchunk = cs ^ ((ri & 3) ^ (ri >> 2));
  const unsigned short* aptr[2];
  const unsigned short* bptr[2];
#pragma unroll
  for (int j = 0; j < 2; j++) {
    int rt = wave * 32 + j * 16 + ri;
    int grow = GATHER ? srows[slot0 + rt] : (slot0 + rt);
    aptr[j] = A + (size_t)grow * KDIM + kchunk * 8;
    bptr[j] = Bte + (size_t)(n0 + rt) * KDIM + kchunk * 8;
  }

  // fragment read offsets (swizzle-aware)
  int l4 = lane & 15, quad = lane >> 4;
  int rchunk = quad ^ ((l4 & 3) ^ (l4 >> 2));
  int wm = wave >> 1, wn = wave & 1;
  int aoffs[4], boffs[4];
#pragma unroll
  for (int i = 0; i < 4; i++) {
    aoffs[i] = (wm * 64 + i * 16 + l4) * 32 + rchunk * 8;
    boffs[i] = 4096 + (wn * 64 + i * 16 + l4) * 32 + rchunk * 8;
  }

  f32x4 zero = {0.f, 0.f, 0.f, 0.f};
  f32x4 acc[4][4];
#pragma unroll
  for (int mi = 0; mi < 4; mi++)
#pragma unroll
    for (int ni = 0; ni < 4; ni++) acc[mi][ni] = zero;

  // prologue: stage k-chunk 0 into buffer 0
  {
    unsigned short* ldsA = &lds[wave * 1024];
    unsigned short* ldsB = &lds[4096 + wave * 1024];
#pragma unroll
    for (int j = 0; j < 2; j++) {
      async_cp16(aptr[j], ldsA + j * 512);
      async_cp16(bptr[j], ldsB + j * 512);
    }
  }

  int it = 0;
  for (int k0 = 0; k0 < KDIM; k0 += 32, it ^= 1) {
    __syncthreads();  // buffer `it` staged (vmcnt drained), prior reads of `it^1` done
    if (k0 + 32 < KDIM) {
      unsigned short* ldsA = &lds[(it ^ 1) * 8192 + wave * 1024];
      unsigned short* ldsB = &lds[(it ^ 1) * 8192 + 4096 + wave * 1024];
#pragma unroll
      for (int j = 0; j < 2; j++) {
        async_cp16(aptr[j] + k0 + 32, ldsA + j * 512);
        async_cp16(bptr[j] + k0 + 32, ldsB + j * 512);
      }
    }
    int base = it * 8192;
    bf16x8 af[4], bfr[4];
#pragma unroll
    for (int i = 0; i < 4; i++) af[i] = *(const bf16x8*)&lds[base + aoffs[i]];
#pragma unroll
    for (int i = 0; i < 4; i++) bfr[i] = *(const bf16x8*)&lds[base + boffs[i]];
#pragma unroll
    for (int mi = 0; mi < 4; mi++)
#pragma unroll
      for (int ni = 0; ni < 4; ni++)
        acc[mi][ni] = __builtin_amdgcn_mfma_f32_16x16x32_bf16(af[mi], bfr[ni], acc[mi][ni], 0, 0, 0);
  }

#pragma unroll
  for (int ni = 0; ni < 4; ni++) {
    int col = n0 + wn * 64 + ni * 16 + l4;
    float bv = bias[e * NDIM + col];
#pragma unroll
    for (int mi = 0; mi < 4; mi++) {
#pragma unroll
      for (int r = 0; r < 4; r++) {
        int srow = slot0 + wm * 64 + mi * 16 + quad * 4 + r;
        float v = acc[mi][ni][r] + bv;
        if (RELU) {
          v = v > 0.f ? v : 0.f;
          Hout[(size_t)srow * NDIM + col] = f2bf(v);
        } else {
          atomicAdd(&Out[(size_t)srows[srow] * ODIM + col], sw[srow] * v);
        }
      }
    }
  }
}

extern "C" void kernel_launch(void* const* d_in, const int* in_sizes, int n_in,
                              void* d_out, int out_size, void* d_ws, size_t ws_size,
                              hipStream_t stream) {
  const float* x  = (const float*)d_in[0];
  const float* Wg = (const float*)d_in[1];
  const float* bg = (const float*)d_in[2];
  const float* W1 = (const float*)d_in[3];
  const float* b1 = (const float*)d_in[4];
  const float* W2 = (const float*)d_in[5];
  const float* b2 = (const float*)d_in[6];
  float* out = (float*)d_out;

  char* ws = (char*)d_ws;
  unsigned short* xb   = (unsigned short*)(ws + O_XB);
  unsigned short* W1t  = (unsigned short*)(ws + O_W1T);
  unsigned short* W2t  = (unsigned short*)(ws + O_W2T);
  unsigned short* hbuf = (unsigned short*)(ws + O_H);
  int*   rowsPE = (int*)(ws + O_ROWSPE);
  float* wPE    = (float*)(ws + O_WPE);
  int*   srows  = (int*)(ws + O_SROWS);
  float* swt    = (float*)(ws + O_SW);
  int*   cnt    = (int*)(ws + O_CNT);
  int*   aoff   = (int*)(ws + O_AOFF);
  int*   toff   = (int*)(ws + O_TOFF);

  hipMemsetAsync(d_out, 0, (size_t)N_ROWS * ODIM * sizeof(float), stream);
  if (ws_size < WS_NEEDED) return;  // loud fail: output stays zero
  hipMemsetAsync(cnt, 0, NEXP * sizeof(int), stream);

  cvt_x_kernel<<<dim3((N_ROWS * DDIM) / (256 * 8)), 256, 0, stream>>>(x, xb);
  transpose_cvt_kernel<<<dim3(DDIM / 64, HDIM / 64, NEXP), 256, 0, stream>>>(W1, W1t, DDIM, HDIM);
  transpose_cvt_kernel<<<dim3(HDIM / 64, ODIM / 64, NEXP), 256, 0, stream>>>(W2, W2t, HDIM, ODIM);
  gate_kernel<<<dim3(N_ROWS / 4), 256, 0, stream>>>(x, Wg, bg, cnt, rowsPE, wPE);
  finalize_kernel<<<1, 64, 0, stream>>>(cnt, aoff, toff);
  scatter_kernel<<<dim3(NEXP), 256, 0, stream>>>(cnt, aoff, rowsPE, wPE, srows, swt);
  gemm_kernel<true, true><<<dim3(136 * (HDIM / 128)), 256, 0, stream>>>(
      xb, W1t, b1, hbuf, nullptr, srows, swt, aoff, toff, DDIM, HDIM, HDIM / 128);
  gemm_kernel<false, false><<<dim3(136 * (ODIM / 128)), 256, 0, stream>>>(
      hbuf, W2t, b2, nullptr, out, srows, swt, aoff, toff, HDIM, ODIM, ODIM / 128);
}

// Round 3
// 1085.425 us; speedup vs baseline: 1.1427x; 1.0075x over previous
//
#include <hip/hip_runtime.h>
#include <hip/hip_bf16.h>

#define N_ROWS 8192
#define DDIM 1024
#define HDIM 4096
#define ODIM 1024
#define NEXP 8

// ws layout (bytes)
#define O_XB      0ull
#define O_W1T     16777216ull
#define O_W2T     83886080ull
#define O_H       150994944ull
#define O_ROWSPE  293601280ull
#define O_WPE     293863424ull
#define O_SROWS   294125568ull
#define O_SW      294195200ull
#define O_CNT     294264832ull
#define O_AOFF    294264864ull
#define O_TOFF    294264904ull
#define WS_NEEDED 294264944ull

typedef short bf16x8 __attribute__((ext_vector_type(8)));
typedef float f32x4 __attribute__((ext_vector_type(4)));

__device__ __forceinline__ unsigned short f2bf(float f) {
  unsigned u = __float_as_uint(f);
  u = (u + 0x7fffu + ((u >> 16) & 1u)) >> 16;
  return (unsigned short)u;
}

__device__ __forceinline__ void async_cp16(const void* g, void* l) {
  __builtin_amdgcn_global_load_lds(
      (const __attribute__((address_space(1))) unsigned int*)g,
      (__attribute__((address_space(3))) unsigned int*)l, 16, 0, 0);
}

// ---- x fp32 -> bf16 ----
__global__ __launch_bounds__(256) void cvt_x_kernel(const float* __restrict__ x,
                                                    unsigned short* __restrict__ xb) {
  size_t i = ((size_t)blockIdx.x * 256 + threadIdx.x) * 8;
  float4 a = *(const float4*)(x + i);
  float4 b = *(const float4*)(x + i + 4);
  union { unsigned short s[8]; uint4 v; } u;
  u.s[0] = f2bf(a.x); u.s[1] = f2bf(a.y); u.s[2] = f2bf(a.z); u.s[3] = f2bf(a.w);
  u.s[4] = f2bf(b.x); u.s[5] = f2bf(b.y); u.s[6] = f2bf(b.z); u.s[7] = f2bf(b.w);
  *(uint4*)(xb + i) = u.v;
}

// ---- per-expert [R,C] fp32 -> [C,R] bf16, vectorized ----
// load: float4 per thread x4 iters; store: bf16x8 packed 16-B stores, coalesced.
__global__ __launch_bounds__(256) void transpose_cvt_kernel(const float* __restrict__ in,
                                                            unsigned short* __restrict__ out,
                                                            int R, int C) {
  __shared__ float t[64][65];
  size_t ebase = (size_t)blockIdx.z * R * C;
  int r0 = blockIdx.x * 64, c0 = blockIdx.y * 64;
  int tid = threadIdx.x;
  int lr = tid >> 4, lc = (tid & 15) * 4;
#pragma unroll
  for (int i = 0; i < 4; i++) {
    int r = i * 16 + lr;
    float4 v = *(const float4*)(in + ebase + (size_t)(r0 + r) * C + (c0 + lc));
    t[r][lc] = v.x; t[r][lc + 1] = v.y; t[r][lc + 2] = v.z; t[r][lc + 3] = v.w;
  }
  __syncthreads();
#pragma unroll
  for (int j = 0; j < 2; j++) {
    int item = tid + j * 256;        // 512 items: 64 cols x 8 row-groups
    int c = item >> 3, r8 = (item & 7) * 8;
    union { unsigned short s[8]; uint4 v; } u;
#pragma unroll
    for (int rr = 0; rr < 8; rr++) u.s[rr] = f2bf(t[r8 + rr][c]);
    *(uint4*)(out + ebase + (size_t)(c0 + c) * R + (r0 + r8)) = u.v;
  }
}

// ---- gating: fp32 GEMV + softmax/T + top2 + renorm; append to per-expert lists ----
__global__ __launch_bounds__(256) void gate_kernel(const float* __restrict__ x,
                                                   const float* __restrict__ Wg,
                                                   const float* __restrict__ bg,
                                                   int* __restrict__ cnt,
                                                   int* __restrict__ rowsPE,
                                                   float* __restrict__ wPE) {
  __shared__ float wgt[NEXP * DDIM];  // transposed [e][d]
  int tid = threadIdx.x;
  for (int i = tid; i < NEXP * DDIM; i += 256) {
    int d = i >> 3, e = i & 7;
    wgt[e * DDIM + d] = Wg[i];
  }
  __syncthreads();
  int lane = tid & 63;
  int row = blockIdx.x * 4 + (tid >> 6);
  const float* xr = x + (size_t)row * DDIM;
  float acc[NEXP];
#pragma unroll
  for (int e = 0; e < NEXP; e++) acc[e] = 0.f;
  for (int j = 0; j < DDIM / 64; j++) {
    int d = j * 64 + lane;
    float xv = xr[d];
#pragma unroll
    for (int e = 0; e < NEXP; e++) acc[e] += xv * wgt[e * DDIM + d];
  }
#pragma unroll
  for (int e = 0; e < NEXP; e++) {
#pragma unroll
    for (int off = 32; off > 0; off >>= 1) acc[e] += __shfl_xor(acc[e], off, 64);
  }
  if (lane == 0) {
    float s[NEXP], p[NEXP];
    float m = -1e30f;
#pragma unroll
    for (int e = 0; e < NEXP; e++) {
      s[e] = (acc[e] + bg[e]) * 0.36787944117144233f;  // 1/TEMP, TEMP=e
      m = s[e] > m ? s[e] : m;
    }
    float sum = 0.f;
#pragma unroll
    for (int e = 0; e < NEXP; e++) { p[e] = __expf(s[e] - m); sum += p[e]; }
    float inv = 1.0f / sum;
#pragma unroll
    for (int e = 0; e < NEXP; e++) p[e] *= inv;
    int i1 = 0;
#pragma unroll
    for (int e = 1; e < NEXP; e++) if (p[e] > p[i1]) i1 = e;
    int i2 = (i1 == 0) ? 1 : 0;
#pragma unroll
    for (int e = 0; e < NEXP; e++) if (e != i1 && p[e] > p[i2]) i2 = e;
    float denom = p[i1] + p[i2] + 1e-8f;
    float w1 = p[i1] / denom, w2 = p[i2] / denom;
    int pos1 = atomicAdd(&cnt[i1], 1);
    rowsPE[i1 * N_ROWS + pos1] = row; wPE[i1 * N_ROWS + pos1] = w1;
    int pos2 = atomicAdd(&cnt[i2], 1);
    rowsPE[i2 * N_ROWS + pos2] = row; wPE[i2 * N_ROWS + pos2] = w2;
  }
}

// ---- 128-aligned prefix offsets ----
__global__ void finalize_kernel(const int* __restrict__ cnt, int* __restrict__ aoff,
                                int* __restrict__ toff) {
  if (threadIdx.x == 0) {
    int a = 0, t = 0;
    for (int e = 0; e < NEXP; e++) {
      aoff[e] = a; toff[e] = t;
      int tiles = (cnt[e] + 127) >> 7;
      a += tiles << 7; t += tiles;
    }
    aoff[NEXP] = a; toff[NEXP] = t;
  }
}

// ---- compact per-expert lists into padded slot arrays ----
__global__ __launch_bounds__(256) void scatter_kernel(const int* __restrict__ cnt,
                                                      const int* __restrict__ aoff,
                                                      const int* __restrict__ rowsPE,
                                                      const float* __restrict__ wPE,
                                                      int* __restrict__ srows,
                                                      float* __restrict__ sw) {
  int e = blockIdx.x;
  int c = cnt[e];
  int padded = ((c + 127) >> 7) << 7;
  int a0 = aoff[e];
  for (int i = threadIdx.x; i < padded; i += 256) {
    if (i < c) { srows[a0 + i] = rowsPE[e * N_ROWS + i]; sw[a0 + i] = wPE[e * N_ROWS + i]; }
    else       { srows[a0 + i] = 0;                      sw[a0 + i] = 0.f; }
  }
}

// ---- grouped GEMM: 128x128 tile, 4 waves, 16x16x32 bf16 MFMA ----
// Double-buffered async LDS staging. Group-swizzled rasterization: within a
// group of GM row-tiles, xt varies fastest -> concurrent blocks share the same
// B K-slice (B fetched from HBM ~once; A tiles stay group-resident in L2/L3).
template <bool GATHER, bool RELU, int GM>
__global__ __launch_bounds__(256) void gemm_kernel(
    const unsigned short* __restrict__ A, const unsigned short* __restrict__ Bt,
    const float* __restrict__ bias, unsigned short* __restrict__ Hout,
    float* __restrict__ Out, const int* __restrict__ srows, const float* __restrict__ sw,
    const int* __restrict__ aoff, const int* __restrict__ toff, int KDIM, int NDIM, int nty) {
  __shared__ unsigned short lds[16384];  // 2 bufs x (A 128x32 @0 | B 128x32 @4096)
  int b = blockIdx.x;
  int perg = GM * nty;
  int g = b / perg, r = b - g * perg;
  int xt = g * GM + (r % GM);
  int yt = r / GM;
  if (xt >= toff[NEXP]) return;
  int e = 0;
  while (toff[e + 1] <= xt) e++;
  int slot0 = aoff[e] + ((xt - toff[e]) << 7);
  int n0 = yt << 7;
  const unsigned short* Bte = Bt + (size_t)e * NDIM * KDIM;

  int tid = threadIdx.x, wave = tid >> 6, lane = tid & 63;
  // staging: lane -> (row-in-issue, chunk-slot); XOR swizzle folded into global addr
  int ri = lane >> 2, cs = lane & 3;
  int kchunk = cs ^ ((ri & 3) ^ (ri >> 2));
  const unsigned short* aptr[2];
  const unsigned short* bptr[2];
#pragma unroll
  for (int j = 0; j < 2; j++) {
    int rt = wave * 32 + j * 16 + ri;
    int grow = GATHER ? srows[slot0 + rt] : (slot0 + rt);
    aptr[j] = A + (size_t)grow * KDIM + kchunk * 8;
    bptr[j] = Bte + (size_t)(n0 + rt) * KDIM + kchunk * 8;
  }

  // fragment read offsets (swizzle-aware)
  int l4 = lane & 15, quad = lane >> 4;
  int rchunk = quad ^ ((l4 & 3) ^ (l4 >> 2));
  int wm = wave >> 1, wn = wave & 1;
  int aoffs[4], boffs[4];
#pragma unroll
  for (int i = 0; i < 4; i++) {
    aoffs[i] = (wm * 64 + i * 16 + l4) * 32 + rchunk * 8;
    boffs[i] = 4096 + (wn * 64 + i * 16 + l4) * 32 + rchunk * 8;
  }

  f32x4 zero = {0.f, 0.f, 0.f, 0.f};
  f32x4 acc[4][4];
#pragma unroll
  for (int mi = 0; mi < 4; mi++)
#pragma unroll
    for (int ni = 0; ni < 4; ni++) acc[mi][ni] = zero;

  // prologue: stage k-chunk 0 into buffer 0
  {
    unsigned short* ldsA = &lds[wave * 1024];
    unsigned short* ldsB = &lds[4096 + wave * 1024];
#pragma unroll
    for (int j = 0; j < 2; j++) {
      async_cp16(aptr[j], ldsA + j * 512);
      async_cp16(bptr[j], ldsB + j * 512);
    }
  }

  int it = 0;
  for (int k0 = 0; k0 < KDIM; k0 += 32, it ^= 1) {
    __syncthreads();  // buffer `it` staged (vmcnt drained), prior reads of `it^1` done
    if (k0 + 32 < KDIM) {
      unsigned short* ldsA = &lds[(it ^ 1) * 8192 + wave * 1024];
      unsigned short* ldsB = &lds[(it ^ 1) * 8192 + 4096 + wave * 1024];
#pragma unroll
      for (int j = 0; j < 2; j++) {
        async_cp16(aptr[j] + k0 + 32, ldsA + j * 512);
        async_cp16(bptr[j] + k0 + 32, ldsB + j * 512);
      }
    }
    int base = it * 8192;
    bf16x8 af[4], bfr[4];
#pragma unroll
    for (int i = 0; i < 4; i++) af[i] = *(const bf16x8*)&lds[base + aoffs[i]];
#pragma unroll
    for (int i = 0; i < 4; i++) bfr[i] = *(const bf16x8*)&lds[base + boffs[i]];
#pragma unroll
    for (int mi = 0; mi < 4; mi++)
#pragma unroll
      for (int ni = 0; ni < 4; ni++)
        acc[mi][ni] = __builtin_amdgcn_mfma_f32_16x16x32_bf16(af[mi], bfr[ni], acc[mi][ni], 0, 0, 0);
  }

#pragma unroll
  for (int ni = 0; ni < 4; ni++) {
    int col = n0 + wn * 64 + ni * 16 + l4;
    float bv = bias[e * NDIM + col];
#pragma unroll
    for (int mi = 0; mi < 4; mi++) {
#pragma unroll
      for (int r2 = 0; r2 < 4; r2++) {
        int srow = slot0 + wm * 64 + mi * 16 + quad * 4 + r2;
        float v = acc[mi][ni][r2] + bv;
        if (RELU) {
          v = v > 0.f ? v : 0.f;
          Hout[(size_t)srow * NDIM + col] = f2bf(v);
        } else {
          atomicAdd(&Out[(size_t)srows[srow] * ODIM + col], sw[srow] * v);
        }
      }
    }
  }
}

extern "C" void kernel_launch(void* const* d_in, const int* in_sizes, int n_in,
                              void* d_out, int out_size, void* d_ws, size_t ws_size,
                              hipStream_t stream) {
  const float* x  = (const float*)d_in[0];
  const float* Wg = (const float*)d_in[1];
  const float* bg = (const float*)d_in[2];
  const float* W1 = (const float*)d_in[3];
  const float* b1 = (const float*)d_in[4];
  const float* W2 = (const float*)d_in[5];
  const float* b2 = (const float*)d_in[6];
  float* out = (float*)d_out;

  char* ws = (char*)d_ws;
  unsigned short* xb   = (unsigned short*)(ws + O_XB);
  unsigned short* W1t  = (unsigned short*)(ws + O_W1T);
  unsigned short* W2t  = (unsigned short*)(ws + O_W2T);
  unsigned short* hbuf = (unsigned short*)(ws + O_H);
  int*   rowsPE = (int*)(ws + O_ROWSPE);
  float* wPE    = (float*)(ws + O_WPE);
  int*   srows  = (int*)(ws + O_SROWS);
  float* swt    = (float*)(ws + O_SW);
  int*   cnt    = (int*)(ws + O_CNT);
  int*   aoff   = (int*)(ws + O_AOFF);
  int*   toff   = (int*)(ws + O_TOFF);

  hipMemsetAsync(d_out, 0, (size_t)N_ROWS * ODIM * sizeof(float), stream);
  if (ws_size < WS_NEEDED) return;  // loud fail: output stays zero
  hipMemsetAsync(cnt, 0, NEXP * sizeof(int), stream);

  cvt_x_kernel<<<dim3((N_ROWS * DDIM) / (256 * 8)), 256, 0, stream>>>(x, xb);
  transpose_cvt_kernel<<<dim3(DDIM / 64, HDIM / 64, NEXP), 256, 0, stream>>>(W1, W1t, DDIM, HDIM);
  transpose_cvt_kernel<<<dim3(HDIM / 64, ODIM / 64, NEXP), 256, 0, stream>>>(W2, W2t, HDIM, ODIM);
  gate_kernel<<<dim3(N_ROWS / 4), 256, 0, stream>>>(x, Wg, bg, cnt, rowsPE, wPE);
  finalize_kernel<<<1, 64, 0, stream>>>(cnt, aoff, toff);
  scatter_kernel<<<dim3(NEXP), 256, 0, stream>>>(cnt, aoff, rowsPE, wPE, srows, swt);
  // grids: ceil(136/GM) groups x GM x nty (excess tiles guarded by toff check)
  constexpr int GM = 16;
  int ng = (136 + GM - 1) / GM;
  gemm_kernel<true, true, GM><<<dim3(ng * GM * (HDIM / 128)), 256, 0, stream>>>(
      xb, W1t, b1, hbuf, nullptr, srows, swt, aoff, toff, DDIM, HDIM, HDIM / 128);
  gemm_kernel<false, false, GM><<<dim3(ng * GM * (ODIM / 128)), 256, 0, stream>>>(
      hbuf, W2t, b2, nullptr, out, srows, swt, aoff, toff, HDIM, ODIM, ODIM / 128);
}